// Round 5
// baseline (30.917 us; speedup 1.0000x reference)
//
#include <hip/hip_runtime.h>
#include <math.h>

#define HH   50
#define NNEG 10
#define EE   128
#define EPSF 1e-6f

// One block (4 waves) per batch element. 16 groups x 16 lanes; lane holds 8
// contiguous floats (2x float4) of a row. SINGLE load pass: tasks 0..49 = his
// rows, 50 = ||src-tar||^2, 51..60 = neg rows (row stashed in registers, dot
// with uhbar finished after the cross-wave exchange). Softmax max-subtraction
// skipped: s2h <= 128*(2/128)^2 ~= 0.031, exp is safe (validated absmax=0).
__global__ __launch_bounds__(256, 8) void htne_kernel(
    const int*   __restrict__ s_nodes,   // [B,1]
    const int*   __restrict__ t_nodes,   // [B,1]
    const float* __restrict__ t_times,   // [B,1]
    const int*   __restrict__ h_nodes,   // [B,H]
    const float* __restrict__ h_times,   // [B,H]
    const float* __restrict__ h_mask,    // [B,H]
    const int*   __restrict__ n_nodes,   // [B,N]
    const float* __restrict__ emb,       // [V,E]
    const float* __restrict__ delta_w,   // [V,1]
    float*       __restrict__ out)       // [B]
{
    __shared__ float s_part[4][EE];      // per-wave unnormalized hbar partials
    __shared__ float s_scw[4][4];        // per-wave SE, UW, UH, UP
    __shared__ float s_s2t;
    __shared__ float s_nl[NNEG];

    const int b    = blockIdx.x;
    const int tid  = threadIdx.x;
    const int wid  = tid >> 6;
    const int lane = tid & 63;
    const int g    = tid >> 4;           // 16-lane group id, 0..15
    const int sub  = tid & 15;           // lane-in-group

    const int   sidx  = s_nodes[b];      // block-uniform -> s_load
    const int   tidx  = t_nodes[b];
    const float tt    = t_times[b];
    const float delta = delta_w[sidx];

    // ---- preload all 4 task row-indices (breaks idx->row dependent chain) ----
    int ridx[4];
    #pragma unroll
    for (int it = 0; it < 4; ++it) {
        const int t = g + it * 16;
        if (t < HH)                     ridx[it] = h_nodes[b * HH + t];
        else if (it == 3 && t > HH && t <= HH + NNEG)
                                        ridx[it] = n_nodes[b * NNEG + (t - HH - 1)];
        else                            ridx[it] = -1;   // t==50 (s2t) or idle
    }

    // per-lane 8-elem slice of src/tar rows (16-way broadcast via L1)
    float sva[8], tva[8];
    {
        float4 a0 = *(const float4*)(emb + (size_t)sidx * EE + sub * 8);
        float4 a1 = *(const float4*)(emb + (size_t)sidx * EE + sub * 8 + 4);
        float4 b0 = *(const float4*)(emb + (size_t)tidx * EE + sub * 8);
        float4 b1 = *(const float4*)(emb + (size_t)tidx * EE + sub * 8 + 4);
        sva[0]=a0.x; sva[1]=a0.y; sva[2]=a0.z; sva[3]=a0.w;
        sva[4]=a1.x; sva[5]=a1.y; sva[6]=a1.z; sva[7]=a1.w;
        tva[0]=b0.x; tva[1]=b0.y; tva[2]=b0.z; tva[3]=b0.w;
        tva[4]=b1.x; tva[5]=b1.y; tva[6]=b1.z; tva[7]=b1.w;
    }

    float SE = 0.f, UW = 0.f, UH = 0.f, UP = 0.f;
    float hb[8] = {0.f,0.f,0.f,0.f,0.f,0.f,0.f,0.f};
    float nv[8];                         // stashed neg row slice (groups 3..12)
    float nA = 0.f, nQ = 0.f;            // reduced ||src-neg||^2, ||neg||^2

    // ---- single pass over 61 tasks (divergence only at it==3, per-group uniform) ----
    #pragma unroll
    for (int it = 0; it < 4; ++it) {
        const int t = g + it * 16;
        if (t < HH) {                    // ---- his row ----
            const float* hrow = emb + (size_t)ridx[it] * EE + sub * 8;
            float4 h0 = *(const float4*)(hrow);
            float4 h1 = *(const float4*)(hrow + 4);
            const float ht = h_times[b * HH + t];   // broadcast loads, overlap
            const float hm = h_mask[b * HH + t];
            float hv[8] = {h0.x,h0.y,h0.z,h0.w,h1.x,h1.y,h1.z,h1.w};
            float a = 0.f, c = 0.f, q = 0.f;
            #pragma unroll
            for (int k = 0; k < 8; ++k) {
                float d1 = hv[k] - sva[k];
                float d2 = hv[k] - tva[k];
                a = fmaf(d1, d1, a);
                c = fmaf(d2, d2, c);
                q = fmaf(hv[k], hv[k], q);
            }
            #pragma unroll
            for (int off = 1; off <= 8; off <<= 1) {
                a += __shfl_xor(a, off);
                c += __shfl_xor(c, off);
                q += __shfl_xor(q, off);
            }
            const float e1 = __expf(-a);
            const float u  = e1 * __expf(delta * fabsf(tt - ht)) * hm;
            SE += e1; UW += u; UH += u * q; UP += u * c;
            #pragma unroll
            for (int k = 0; k < 8; ++k) hb[k] = fmaf(u, hv[k], hb[k]);
        } else if (it == 3) {
            if (t == HH) {               // ---- ||src-tar||^2 (group 2) ----
                float a = 0.f;
                #pragma unroll
                for (int k = 0; k < 8; ++k) {
                    float d = sva[k] - tva[k];
                    a = fmaf(d, d, a);
                }
                #pragma unroll
                for (int off = 1; off <= 8; off <<= 1) a += __shfl_xor(a, off);
                if (sub == 0) s_s2t = a;
            } else if (t <= HH + NNEG) { // ---- neg row (groups 3..12): stash ----
                const float* nrow = emb + (size_t)ridx[it] * EE + sub * 8;
                float4 n0 = *(const float4*)(nrow);
                float4 n1 = *(const float4*)(nrow + 4);
                nv[0]=n0.x; nv[1]=n0.y; nv[2]=n0.z; nv[3]=n0.w;
                nv[4]=n1.x; nv[5]=n1.y; nv[6]=n1.z; nv[7]=n1.w;
                float a = 0.f, q = 0.f;
                #pragma unroll
                for (int k = 0; k < 8; ++k) {
                    float d1 = nv[k] - sva[k];
                    a = fmaf(d1, d1, a);
                    q = fmaf(nv[k], nv[k], q);
                }
                #pragma unroll
                for (int off = 1; off <= 8; off <<= 1) {
                    a += __shfl_xor(a, off);
                    q += __shfl_xor(q, off);
                }
                nA = a; nQ = q;          // group-uniform after reduce
            }
        }
    }

    // ---- cross-group butterfly (xor 16, 32): wave-level partials ----
    #pragma unroll
    for (int off = 16; off <= 32; off <<= 1) {
        SE += __shfl_xor(SE, off);
        UW += __shfl_xor(UW, off);
        UH += __shfl_xor(UH, off);
        UP += __shfl_xor(UP, off);
        #pragma unroll
        for (int k = 0; k < 8; ++k) hb[k] += __shfl_xor(hb[k], off);
    }
    if (lane < 16) {
        *(float4*)(&s_part[wid][sub * 8])     = make_float4(hb[0],hb[1],hb[2],hb[3]);
        *(float4*)(&s_part[wid][sub * 8 + 4]) = make_float4(hb[4],hb[5],hb[6],hb[7]);
    }
    if (lane == 0) {
        s_scw[wid][0] = SE; s_scw[wid][1] = UW;
        s_scw[wid][2] = UH; s_scw[wid][3] = UP;
    }
    __syncthreads();

    const float SEt = s_scw[0][0] + s_scw[1][0] + s_scw[2][0] + s_scw[3][0];
    const float UWt = s_scw[0][1] + s_scw[1][1] + s_scw[2][1] + s_scw[3][1];
    const float UHt = s_scw[0][2] + s_scw[1][2] + s_scw[2][2] + s_scw[3][2];

    // ---- finish negs from stashed registers (no second gather) ----
    if (g >= 3 && g <= 12) {
        float d = 0.f;
        #pragma unroll
        for (int k = 0; k < 8; ++k) {
            float hbs = s_part[0][sub*8+k] + s_part[1][sub*8+k]
                      + s_part[2][sub*8+k] + s_part[3][sub*8+k];
            d = fmaf(hbs, nv[k], d);
        }
        #pragma unroll
        for (int off = 1; off <= 8; off <<= 1) d += __shfl_xor(d, off);
        if (sub == 0) {
            float nl = -nA - (UHt + nQ * UWt - 2.f * d) / SEt;   // n_lambda
            s_nl[g - 3] = __logf(1.f / (1.f + __expf(nl)) + EPSF);
        }
    }
    __syncthreads();

    // ---- final combine (thread 0) ----
    if (tid == 0) {
        const float UPt = s_scw[0][3] + s_scw[1][3] + s_scw[2][3] + s_scw[3][3];
        float neg_loss = 0.f;
        #pragma unroll
        for (int n = 0; n < NNEG; ++n) neg_loss += s_nl[n];
        float pl = -s_s2t - UPt / SEt;                           // p_lambda
        float pos_loss = -__logf(1.f / (1.f + __expf(-pl)) + EPSF);
        out[b] = pos_loss - neg_loss;
    }
}

extern "C" void kernel_launch(void* const* d_in, const int* in_sizes, int n_in,
                              void* d_out, int out_size, void* d_ws, size_t ws_size,
                              hipStream_t stream) {
    const int*   s_nodes = (const int*)  d_in[0];
    const int*   t_nodes = (const int*)  d_in[1];
    const float* t_times = (const float*)d_in[2];
    const int*   h_nodes = (const int*)  d_in[3];
    const float* h_times = (const float*)d_in[4];
    const float* h_mask  = (const float*)d_in[5];
    const int*   n_nodes = (const int*)  d_in[6];
    const float* emb     = (const float*)d_in[7];
    const float* delta_w = (const float*)d_in[8];
    float*       out     = (float*)d_out;

    const int Bn = in_sizes[0];  // 4096
    htne_kernel<<<Bn, 256, 0, stream>>>(s_nodes, t_nodes, t_times, h_nodes,
                                        h_times, h_mask, n_nodes, emb, delta_w, out);
}